// Round 12
// baseline (573.034 us; speedup 1.0000x reference)
//
#include <hip/hip_runtime.h>
#include <math.h>

namespace {

constexpr int       kNME    = 262144;
constexpr int       kNDOF   = 524288;
constexpr long long kNNZ    = 16777216;   // kNME * 64
constexpr int       kNB     = 64;         // buckets
constexpr int       kBShift = 13;         // 8192 dofs / bucket
constexpr int       kBSpan  = 8192;
constexpr int       kEnt    = 2048;       // entries per producer block
constexpr int       kPerTh  = 8;          // kEnt / 256
constexpr int       kCtrStride = 16;      // counters padded to 64 B

constexpr float kEmin    = 1e-9f;
constexpr float kEmax    = 1.0f;
constexpr float kVolfrac = 0.4f;

using u32   = unsigned;
using i32x4 = __attribute__((ext_vector_type(4))) int;
using f32x4 = __attribute__((ext_vector_type(4))) float;
using u32x4 = __attribute__((ext_vector_type(4))) unsigned;

// pair = (localrow:13 bits << 19) | (fp32 bits >> 13)  [sign+exp+10 mantissa]
__device__ __forceinline__ u32 pack32(unsigned localrow, float v) {
    return (localrow << 19) | (__float_as_uint(v) >> 13);
}

// ---------------------------------------------------------------------------
// Kernel 1: per-element SIMP scale + rho partial sum.  (round-8 exact)
// ---------------------------------------------------------------------------
__global__ void scale_kernel(const float* __restrict__ W_x,
                             float* __restrict__ scale,
                             float* __restrict__ rho_sum) {
    int i = blockIdx.x * blockDim.x + threadIdx.x;
    float rho = 0.0f;
    if (i < kNME) {
        float x = W_x[i];
        rho = 1.0f / (1.0f + __expf(-x));
        scale[i] = kEmin + rho * rho * rho * (kEmax - kEmin);
    }
    for (int off = 32; off > 0; off >>= 1) rho += __shfl_down(rho, off, 64);
    __shared__ float partial[4];
    const int lane = threadIdx.x & 63;
    const int wid  = threadIdx.x >> 6;
    if (lane == 0) partial[wid] = rho;
    __syncthreads();
    if (threadIdx.x == 0)
        atomicAdd(rho_sum, partial[0] + partial[1] + partial[2] + partial[3]);
}

// ---------------------------------------------------------------------------
// Producer (round-8 exact, measured 136 us): vectorized staging loads; hist
// atomicAdd doubles as rank; 4B packed pairs; per-bucket run copy-out.
// rv[j]: bits[0:18] = row (19b), bits[19:30] = rank (12b).
// ---------------------------------------------------------------------------
__global__ __launch_bounds__(256, 8)
void producer_kernel(const float* __restrict__ K_sep,
                     const int*   __restrict__ rows,
                     const int*   __restrict__ cols,
                     const float* __restrict__ u,
                     const float* __restrict__ scale,
                     u32*         __restrict__ pairs,
                     unsigned*    __restrict__ counters,  // [kNB*R*kCtrStride]
                     long long chunk_base, unsigned capSub, int R) {
    __shared__ unsigned hist[kNB], ofs[kNB], gbase[kNB];
    __shared__ u32      sorted[kEnt];     // 8 KB

    const int tid = threadIdx.x;
    const int sub = blockIdx.x & (R - 1);
    if (tid < kNB) hist[tid] = 0u;
    __syncthreads();

    const long long i0 =
        chunk_base + (long long)blockIdx.x * kEnt + (long long)tid * kPerTh;
    i32x4 r0 = __builtin_nontemporal_load((const i32x4*)(rows + i0));
    i32x4 r1 = __builtin_nontemporal_load((const i32x4*)(rows + i0) + 1);
    i32x4 c0 = __builtin_nontemporal_load((const i32x4*)(cols + i0));
    i32x4 c1 = __builtin_nontemporal_load((const i32x4*)(cols + i0) + 1);
    f32x4 k0 = __builtin_nontemporal_load((const f32x4*)(K_sep + i0));
    f32x4 k1 = __builtin_nontemporal_load((const f32x4*)(K_sep + i0) + 1);
    const float s = scale[(int)(i0 >> 6)];   // all 8 share one element

    unsigned rv[kPerTh];
    float    vv[kPerTh];
#pragma unroll
    for (int j = 0; j < 4; ++j) {
        rv[j]     = (unsigned)r0[j];  vv[j]     = k0[j] * s * u[c0[j]];
        rv[j + 4] = (unsigned)r1[j];  vv[j + 4] = k1[j] * s * u[c1[j]];
    }
    // Histogram; the returned old value IS this entry's rank in its bucket.
#pragma unroll
    for (int j = 0; j < kPerTh; ++j)
        rv[j] |= atomicAdd(&hist[rv[j] >> kBShift], 1u) << 19;
    __syncthreads();

    // Wave 0: exclusive scan over 64 buckets + reserve global sub-ranges.
    if (tid < kNB) {
        unsigned h = hist[tid];
        unsigned x = h;
#pragma unroll
        for (int off = 1; off < kNB; off <<= 1) {
            unsigned y = __shfl_up(x, off, 64);
            if (tid >= off) x += y;
        }
        ofs[tid]   = x - h;
        gbase[tid] = atomicAdd(&counters[(tid * R + sub) * kCtrStride], h);
    }
    __syncthreads();

    // Scatter into sorted LDS order — no atomics (rank precomputed).
#pragma unroll
    for (int j = 0; j < kPerTh; ++j) {
        unsigned row = rv[j] & 0x7FFFFu;
        unsigned b   = row >> kBShift;
        unsigned pos = ofs[b] + (rv[j] >> 19);
        sorted[pos]  = pack32(row & (kBSpan - 1), vv[j]);
    }
    __syncthreads();

    // Coalesced copy-out: one wave per bucket run.
    const int wid = tid >> 6, lane = tid & 63;
    for (int b = wid; b < kNB; b += 4) {
        const unsigned s0 = ofs[b];
        const unsigned n  = hist[b];
        const unsigned g  = gbase[b];
        u32* dst = pairs + (size_t)(b * R + sub) * capSub + g;
        for (unsigned i = lane; i < n; i += 64) {
            if (g + i < capSub)
                __builtin_nontemporal_store(sorted[s0 + i], &dst[i]);
        }
    }
}

// ---------------------------------------------------------------------------
// Consumer (round-8 structure) + fused per-bucket norm.  Block (b, sub)
// accumulates its sub-region into a 32 KB LDS tile and stores its private
// partial plane.  The LAST of the R blocks for bucket b (per-bucket done
// counter) re-reads the R planes (L2/L3-hot) and adds this bucket's
// sum((Ku-f)^2); the globally-last bucket writes the final loss.
// acc layout: acc[0]=rho_sum, acc[1]=norm_sum, acc[2]=done buckets (uint).
// ---------------------------------------------------------------------------
__global__ __launch_bounds__(512, 8)
void consumer_norm_kernel(const u32*      __restrict__ pairs,
                          const unsigned* __restrict__ counters,
                          float*          __restrict__ partial,
                          const float*    __restrict__ f,
                          float*          __restrict__ acc_g,
                          unsigned*       __restrict__ bucket_done,
                          float*          __restrict__ out,
                          unsigned capSub, int R) {
    const int b   = blockIdx.x / R;
    const int sub = blockIdx.x - b * R;
    unsigned cnt = counters[(b * R + sub) * kCtrStride];
    if (cnt > capSub) cnt = capSub;

    __shared__ float acc[kBSpan];        // 32 KB
    __shared__ float wpart[8];
    __shared__ unsigned lastflag;
    for (int i = threadIdx.x; i < kBSpan; i += 512) acc[i] = 0.0f;
    __syncthreads();

    const u32* p = pairs + (size_t)(b * R + sub) * capSub;
    const unsigned aligned = cnt & ~3u;
    for (unsigned i = 4 * threadIdx.x; i < aligned; i += 2048) {
        u32x4 e = __builtin_nontemporal_load((const u32x4*)(p + i));
#pragma unroll
        for (int j = 0; j < 4; ++j)
            atomicAdd(&acc[e[j] >> 19], __uint_as_float(e[j] << 13));
    }
    if (threadIdx.x < (cnt - aligned)) {
        u32 e = p[aligned + threadIdx.x];
        atomicAdd(&acc[e >> 19], __uint_as_float(e << 13));
    }
    __syncthreads();

    // Publish this sub's plane.
    float* dst = partial + (size_t)(b * R + sub) * kBSpan;
    for (int k = threadIdx.x; k < kBSpan; k += 512) dst[k] = acc[k];
    __threadfence();
    if (threadIdx.x == 0)
        lastflag = (atomicAdd(&bucket_done[b], 1u) == (unsigned)(R - 1));
    __syncthreads();
    if (!lastflag) return;
    __threadfence();   // acquire: planes from other blocks now visible

    // Norm for bucket b: sum R planes per dof, (sum - f)^2.
    float a = 0.0f;
    const float* fb = f + (size_t)b * kBSpan;
    for (int k = 4 * (int)threadIdx.x; k < kBSpan; k += 2048) {
        f32x4 s = {0.0f, 0.0f, 0.0f, 0.0f};
        for (int r = 0; r < R; ++r)
            s += *(const f32x4*)(partial + (size_t)(b * R + r) * kBSpan + k);
        f32x4 fv = *(const f32x4*)(fb + k);
        f32x4 d  = s - fv;
        a += d[0] * d[0] + d[1] * d[1] + d[2] * d[2] + d[3] * d[3];
    }
    for (int off = 32; off > 0; off >>= 1) a += __shfl_down(a, off, 64);
    const int lane = threadIdx.x & 63, wid = threadIdx.x >> 6;
    if (lane == 0) wpart[wid] = a;
    __syncthreads();
    if (threadIdx.x == 0) {
        float t = 0.0f;
#pragma unroll
        for (int w = 0; w < 8; ++w) t += wpart[w];
        atomicAdd(&acc_g[1], t);
        __threadfence();
        unsigned done = atomicAdd((unsigned*)&acc_g[2], 1u);
        if (done == (unsigned)(kNB - 1)) {
            float rs = __hip_atomic_load(&acc_g[0], __ATOMIC_RELAXED,
                                         __HIP_MEMORY_SCOPE_AGENT);
            float ns = __hip_atomic_load(&acc_g[1], __ATOMIC_RELAXED,
                                         __HIP_MEMORY_SCOPE_AGENT);
            float rho_mean = rs * (1.0f / (float)kNME);
            out[0] = fmaxf(rho_mean - kVolfrac, 0.0f) + sqrtf(ns);
        }
    }
}

// ---------------------------------------------------------------------------
// Fallback path (device atomics) if workspace is too small.
// ---------------------------------------------------------------------------
__global__ void scatter_dev_kernel(const float* __restrict__ K_sep,
                                   const int*   __restrict__ rows,
                                   const int*   __restrict__ cols,
                                   const float* __restrict__ u,
                                   const float* __restrict__ scale,
                                   float* __restrict__ Ku) {
    long long i = (long long)blockIdx.x * blockDim.x + threadIdx.x;
    if (i >= kNNZ) return;
    float s = scale[(int)(i >> 6)];
    atomicAdd(&Ku[rows[i]], K_sep[i] * s * u[cols[i]]);
}

__global__ void norm1_kernel(const float* __restrict__ Ku,
                             const float* __restrict__ f,
                             float* __restrict__ norm_sum) {
    float a = 0.0f;
    for (int i = blockIdx.x * blockDim.x + threadIdx.x; i < kNDOF;
         i += gridDim.x * blockDim.x) {
        float d = Ku[i] - f[i];
        a += d * d;
    }
    for (int off = 32; off > 0; off >>= 1) a += __shfl_down(a, off, 64);
    __shared__ float partial_s[4];
    const int lane = threadIdx.x & 63;
    const int wid  = threadIdx.x >> 6;
    if (lane == 0) partial_s[wid] = a;
    __syncthreads();
    if (threadIdx.x == 0)
        atomicAdd(norm_sum,
                  partial_s[0] + partial_s[1] + partial_s[2] + partial_s[3]);
}

__global__ void finalize_kernel(const float* __restrict__ acc,
                                float* __restrict__ out) {
    if (threadIdx.x == 0 && blockIdx.x == 0) {
        float rho_mean = acc[0] * (1.0f / (float)kNME);
        float vol = fmaxf(rho_mean - kVolfrac, 0.0f);
        out[0] = vol + sqrtf(acc[1]);
    }
}

}  // namespace

extern "C" void kernel_launch(void* const* d_in, const int* in_sizes, int n_in,
                              void* d_out, int out_size, void* d_ws, size_t ws_size,
                              hipStream_t stream) {
    const float* W_x   = (const float*)d_in[0];
    const float* K_sep = (const float*)d_in[1];
    const int*   idx   = (const int*)d_in[2];
    const float* u     = (const float*)d_in[3];
    const float* f     = (const float*)d_in[4];
    const int* rows = idx;
    const int* cols = idx + kNNZ;

    float* ws = (float*)d_ws;
    const size_t avail = ws_size / sizeof(float);

    // Single-chunk config (round 8 proven): R=16 subs, margin 2048.
    const int      R      = 16;
    const unsigned capSub = (unsigned)(kNNZ / (kNB * R)) + 2048;
    const size_t   ctrF   = (size_t)kNB * R * kCtrStride;          // 16384
    const size_t   headF  = 96;                                    // acc+done+pad
    const size_t   partF  = (size_t)kNB * R * kBSpan;              // 8.4M
    const size_t   need   = headF + ctrF + partF + kNME +
                            (size_t)kNB * R * capSub;

    if (need > avail) {
        // Fallback: device-atomic scatter (fits in ~3.2 MB).
        float* Ku    = ws;
        float* scale = ws + kNDOF;
        float* acc   = ws + kNDOF + kNME;
        hipMemsetAsync(ws, 0, (size_t)(kNDOF + kNME + 16) * sizeof(float), stream);
        scale_kernel<<<kNME / 256, 256, 0, stream>>>(W_x, scale, acc);
        scatter_dev_kernel<<<(int)(kNNZ / 256), 256, 0, stream>>>(
            K_sep, rows, cols, u, scale, Ku);
        norm1_kernel<<<2048, 256, 0, stream>>>(Ku, f, acc + 1);
        finalize_kernel<<<1, 64, 0, stream>>>(acc, (float*)d_out);
        return;
    }

    float*    acc         = ws;                       // [16] rho,norm,done
    unsigned* bucket_done = (unsigned*)(ws + 16);     // [64]
    unsigned* counters    = (unsigned*)(ws + headF);  // [kNB*R*kCtrStride]
    float*    partial     = ws + headF + ctrF;        // [kNB*R*kBSpan]
    float*    scale       = partial + partF;          // [kNME]
    u32*      pairs       = (u32*)(scale + kNME);     // [kNB*R*capSub]

    // Zero acc + bucket_done + counters (replay-safe).
    hipMemsetAsync(ws, 0, (headF + ctrF) * sizeof(float), stream);

    scale_kernel<<<kNME / 256, 256, 0, stream>>>(W_x, scale, acc);

    producer_kernel<<<(int)(kNNZ / kEnt), 256, 0, stream>>>(
        K_sep, rows, cols, u, scale, pairs, counters, 0LL, capSub, R);

    consumer_norm_kernel<<<kNB * R, 512, 0, stream>>>(
        pairs, counters, partial, f, acc, bucket_done, (float*)d_out,
        capSub, R);
}

// Round 13
// 255.811 us; speedup vs baseline: 2.2401x; 2.2401x over previous
//
#include <hip/hip_runtime.h>
#include <math.h>

namespace {

constexpr int       kNME    = 262144;
constexpr int       kNDOF   = 524288;
constexpr long long kNNZ    = 16777216;   // kNME * 64
constexpr int       kNB     = 64;         // buckets
constexpr int       kBShift = 13;         // 8192 dofs / bucket
constexpr int       kBSpan  = 8192;
constexpr int       kEnt    = 8192;       // entries per producer block
constexpr int       kPTh   = 1024;        // producer threads
constexpr int       kPerTh  = 8;          // kEnt / kPTh
constexpr int       kCtrStride = 16;      // counters padded to 64 B

constexpr float kEmin    = 1e-9f;
constexpr float kEmax    = 1.0f;
constexpr float kVolfrac = 0.4f;

using u32   = unsigned;
using i32x4 = __attribute__((ext_vector_type(4))) int;
using f32x4 = __attribute__((ext_vector_type(4))) float;
using u32x4 = __attribute__((ext_vector_type(4))) unsigned;

// pair = (localrow:13 bits << 19) | (fp32 bits >> 13)  [sign+exp+10 mantissa]
__device__ __forceinline__ u32 pack32(unsigned localrow, float v) {
    return (localrow << 19) | (__float_as_uint(v) >> 13);
}

// ---------------------------------------------------------------------------
// Kernel 1: per-element SIMP scale + rho partial sum.
// ---------------------------------------------------------------------------
__global__ void scale_kernel(const float* __restrict__ W_x,
                             float* __restrict__ scale,
                             float* __restrict__ rho_sum) {
    int i = blockIdx.x * blockDim.x + threadIdx.x;
    float rho = 0.0f;
    if (i < kNME) {
        float x = W_x[i];
        rho = 1.0f / (1.0f + __expf(-x));
        scale[i] = kEmin + rho * rho * rho * (kEmax - kEmin);
    }
    for (int off = 32; off > 0; off >>= 1) rho += __shfl_down(rho, off, 64);
    __shared__ float partial[4];
    const int lane = threadIdx.x & 63;
    const int wid  = threadIdx.x >> 6;
    if (lane == 0) partial[wid] = rho;
    __syncthreads();
    if (threadIdx.x == 0)
        atomicAdd(rho_sum, partial[0] + partial[1] + partial[2] + partial[3]);
}

// ---------------------------------------------------------------------------
// Producer: 1024 threads x 8 entries = 8192/block.  Round-8 mechanics (hist
// atomicAdd doubles as rank; LDS sort; coalesced run copy-out), but runs are
// now ~128 entries (512 B) -> far less partial-line write waste.
// rv[j]: bits[0:18] = row (19b), bits[19:31] = rank (13b, max 8191).
// ---------------------------------------------------------------------------
__global__ __launch_bounds__(kPTh, 8)
void producer_kernel(const float* __restrict__ K_sep,
                     const int*   __restrict__ rows,
                     const int*   __restrict__ cols,
                     const float* __restrict__ u,
                     const float* __restrict__ scale,
                     u32*         __restrict__ pairs,
                     unsigned*    __restrict__ counters,  // [kNB*R*kCtrStride]
                     unsigned capSub, int R) {
    __shared__ unsigned hist[kNB], ofs[kNB], gbase[kNB];
    __shared__ u32      sorted[kEnt];     // 32 KB

    const int tid = threadIdx.x;
    const int sub = blockIdx.x & (R - 1);
    if (tid < kNB) hist[tid] = 0u;
    __syncthreads();

    const long long i0 =
        (long long)blockIdx.x * kEnt + (long long)tid * kPerTh;
    i32x4 r0 = __builtin_nontemporal_load((const i32x4*)(rows + i0));
    i32x4 r1 = __builtin_nontemporal_load((const i32x4*)(rows + i0) + 1);
    i32x4 c0 = __builtin_nontemporal_load((const i32x4*)(cols + i0));
    i32x4 c1 = __builtin_nontemporal_load((const i32x4*)(cols + i0) + 1);
    f32x4 k0 = __builtin_nontemporal_load((const f32x4*)(K_sep + i0));
    f32x4 k1 = __builtin_nontemporal_load((const f32x4*)(K_sep + i0) + 1);
    const float s = scale[(int)(i0 >> 6)];   // all 8 share one element

    unsigned rv[kPerTh];
    float    vv[kPerTh];
#pragma unroll
    for (int j = 0; j < 4; ++j) {
        rv[j]     = (unsigned)r0[j];  vv[j]     = k0[j] * s * u[c0[j]];
        rv[j + 4] = (unsigned)r1[j];  vv[j + 4] = k1[j] * s * u[c1[j]];
    }
    // Histogram; the returned old value IS this entry's rank in its bucket.
#pragma unroll
    for (int j = 0; j < kPerTh; ++j)
        rv[j] |= atomicAdd(&hist[rv[j] >> kBShift], 1u) << 19;
    __syncthreads();

    // Threads 0..63: exclusive scan over buckets + reserve global sub-ranges.
    if (tid < kNB) {
        unsigned h = hist[tid];
        unsigned x = h;
#pragma unroll
        for (int off = 1; off < kNB; off <<= 1) {
            unsigned y = __shfl_up(x, off, 64);
            if (tid >= off) x += y;
        }
        ofs[tid]   = x - h;
        gbase[tid] = atomicAdd(&counters[(tid * R + sub) * kCtrStride], h);
    }
    __syncthreads();

    // Scatter into sorted LDS order — no atomics (rank precomputed).
#pragma unroll
    for (int j = 0; j < kPerTh; ++j) {
        unsigned row = rv[j] & 0x7FFFFu;
        unsigned b   = row >> kBShift;
        unsigned pos = ofs[b] + (rv[j] >> 19);
        sorted[pos]  = pack32(row & (kBSpan - 1), vv[j]);
    }
    __syncthreads();

    // Coalesced copy-out: 16 waves, 4 bucket runs each (~128 entries/run).
    const int wid = tid >> 6, lane = tid & 63;
    for (int b = wid; b < kNB; b += 16) {
        const unsigned s0 = ofs[b];
        const unsigned n  = hist[b];
        const unsigned g  = gbase[b];
        u32* dst = pairs + (size_t)(b * R + sub) * capSub + g;
        for (unsigned i = lane; i < n; i += 64) {
            if (g + i < capSub)
                __builtin_nontemporal_store(sorted[s0 + i], &dst[i]);
        }
    }
}

// ---------------------------------------------------------------------------
// Consumer (round-8 exact): block (b, sub) owns one sub-region. 512 threads,
// u32x4 loads, fire-and-forget LDS atomics, private store of its plane.
// ---------------------------------------------------------------------------
__global__ __launch_bounds__(512, 8)
void consumer_kernel(const u32*      __restrict__ pairs,
                     const unsigned* __restrict__ counters,
                     float*          __restrict__ partial,
                     unsigned capSub, int R) {
    const int b   = blockIdx.x / R;
    const int sub = blockIdx.x - b * R;
    unsigned cnt = counters[(b * R + sub) * kCtrStride];
    if (cnt > capSub) cnt = capSub;

    __shared__ float acc[kBSpan];
    for (int i = threadIdx.x; i < kBSpan; i += 512) acc[i] = 0.0f;
    __syncthreads();

    const u32* p = pairs + (size_t)(b * R + sub) * capSub;
    const unsigned aligned = cnt & ~3u;
    for (unsigned i = 4 * threadIdx.x; i < aligned; i += 2048) {
        u32x4 e = __builtin_nontemporal_load((const u32x4*)(p + i));
#pragma unroll
        for (int j = 0; j < 4; ++j)
            atomicAdd(&acc[e[j] >> 19], __uint_as_float(e[j] << 13));
    }
    if (threadIdx.x < (cnt - aligned)) {
        u32 e = p[aligned + threadIdx.x];
        atomicAdd(&acc[e >> 19], __uint_as_float(e << 13));
    }
    __syncthreads();

    float* dst = partial + (size_t)(b * R + sub) * kBSpan;
    for (int k = threadIdx.x; k < kBSpan; k += 512) dst[k] = acc[k];
}

// ---------------------------------------------------------------------------
// Norm + finalize (round-10 proven): block (b, chunk of 1024 dofs);
// vectorized sum over R planes; done-counter finalize (thread 0 only).
// acc layout: acc[0]=rho_sum, acc[1]=norm_sum, acc[2]=done counter (uint).
// ---------------------------------------------------------------------------
__global__ void norm_kernel(const float* __restrict__ partial,
                            const float* __restrict__ f,
                            float* __restrict__ acc,
                            float* __restrict__ out, int R) {
    const int b  = blockIdx.x >> 3;
    const int i0 = (blockIdx.x & 7) * 1024 + threadIdx.x * 4;
    f32x4 s = {0.0f, 0.0f, 0.0f, 0.0f};
    for (int r = 0; r < R; ++r)
        s += *(const f32x4*)(partial + (size_t)(b * R + r) * kBSpan + i0);
    f32x4 fv = *(const f32x4*)(f + (size_t)b * kBSpan + i0);
    f32x4 d  = s - fv;
    float a = d[0] * d[0] + d[1] * d[1] + d[2] * d[2] + d[3] * d[3];
    for (int off = 32; off > 0; off >>= 1) a += __shfl_down(a, off, 64);
    __shared__ float partial_s[4];
    const int lane = threadIdx.x & 63;
    const int wid  = threadIdx.x >> 6;
    if (lane == 0) partial_s[wid] = a;
    __syncthreads();
    if (threadIdx.x == 0) {
        atomicAdd(&acc[1],
                  partial_s[0] + partial_s[1] + partial_s[2] + partial_s[3]);
        __threadfence();
        unsigned done = atomicAdd((unsigned*)&acc[2], 1u);
        if (done == gridDim.x - 1) {
            float rs = __hip_atomic_load(&acc[0], __ATOMIC_RELAXED,
                                         __HIP_MEMORY_SCOPE_AGENT);
            float ns = __hip_atomic_load(&acc[1], __ATOMIC_RELAXED,
                                         __HIP_MEMORY_SCOPE_AGENT);
            float rho_mean = rs * (1.0f / (float)kNME);
            out[0] = fmaxf(rho_mean - kVolfrac, 0.0f) + sqrtf(ns);
        }
    }
}

// ---------------------------------------------------------------------------
// Fallback path (device atomics) if workspace is too small.
// ---------------------------------------------------------------------------
__global__ void scatter_dev_kernel(const float* __restrict__ K_sep,
                                   const int*   __restrict__ rows,
                                   const int*   __restrict__ cols,
                                   const float* __restrict__ u,
                                   const float* __restrict__ scale,
                                   float* __restrict__ Ku) {
    long long i = (long long)blockIdx.x * blockDim.x + threadIdx.x;
    if (i >= kNNZ) return;
    float s = scale[(int)(i >> 6)];
    atomicAdd(&Ku[rows[i]], K_sep[i] * s * u[cols[i]]);
}

__global__ void norm1_kernel(const float* __restrict__ Ku,
                             const float* __restrict__ f,
                             float* __restrict__ norm_sum) {
    float a = 0.0f;
    for (int i = blockIdx.x * blockDim.x + threadIdx.x; i < kNDOF;
         i += gridDim.x * blockDim.x) {
        float d = Ku[i] - f[i];
        a += d * d;
    }
    for (int off = 32; off > 0; off >>= 1) a += __shfl_down(a, off, 64);
    __shared__ float partial_s[4];
    const int lane = threadIdx.x & 63;
    const int wid  = threadIdx.x >> 6;
    if (lane == 0) partial_s[wid] = a;
    __syncthreads();
    if (threadIdx.x == 0)
        atomicAdd(norm_sum,
                  partial_s[0] + partial_s[1] + partial_s[2] + partial_s[3]);
}

__global__ void finalize_kernel(const float* __restrict__ acc,
                                float* __restrict__ out) {
    if (threadIdx.x == 0 && blockIdx.x == 0) {
        float rho_mean = acc[0] * (1.0f / (float)kNME);
        float vol = fmaxf(rho_mean - kVolfrac, 0.0f);
        out[0] = vol + sqrtf(acc[1]);
    }
}

}  // namespace

extern "C" void kernel_launch(void* const* d_in, const int* in_sizes, int n_in,
                              void* d_out, int out_size, void* d_ws, size_t ws_size,
                              hipStream_t stream) {
    const float* W_x   = (const float*)d_in[0];
    const float* K_sep = (const float*)d_in[1];
    const int*   idx   = (const int*)d_in[2];
    const float* u     = (const float*)d_in[3];
    const float* f     = (const float*)d_in[4];
    const int* rows = idx;
    const int* cols = idx + kNNZ;

    float* ws = (float*)d_ws;
    const size_t avail = ws_size / sizeof(float);

    // Single-chunk config (round 8 proven): R=16 subs, margin 2048.
    const int      R      = 16;
    const unsigned capSub = (unsigned)(kNNZ / (kNB * R)) + 2048;
    const size_t   ctrF   = (size_t)kNB * R * kCtrStride;          // 16384
    const size_t   headF  = 16;                                    // acc
    const size_t   partF  = (size_t)kNB * R * kBSpan;              // 8.4M
    const size_t   need   = headF + ctrF + partF + kNME +
                            (size_t)kNB * R * capSub;

    if (need > avail) {
        // Fallback: device-atomic scatter (fits in ~3.2 MB).
        float* Ku    = ws;
        float* scale = ws + kNDOF;
        float* acc   = ws + kNDOF + kNME;
        hipMemsetAsync(ws, 0, (size_t)(kNDOF + kNME + 16) * sizeof(float), stream);
        scale_kernel<<<kNME / 256, 256, 0, stream>>>(W_x, scale, acc);
        scatter_dev_kernel<<<(int)(kNNZ / 256), 256, 0, stream>>>(
            K_sep, rows, cols, u, scale, Ku);
        norm1_kernel<<<2048, 256, 0, stream>>>(Ku, f, acc + 1);
        finalize_kernel<<<1, 64, 0, stream>>>(acc, (float*)d_out);
        return;
    }

    float*    acc      = ws;                          // [16] rho,norm,done
    unsigned* counters = (unsigned*)(ws + headF);     // [kNB*R*kCtrStride]
    float*    partial  = ws + headF + ctrF;           // [kNB*R*kBSpan]
    float*    scale    = partial + partF;             // [kNME]
    u32*      pairs    = (u32*)(scale + kNME);        // [kNB*R*capSub]

    // Zero acc + counters (replay-safe).
    hipMemsetAsync(ws, 0, (headF + ctrF) * sizeof(float), stream);

    scale_kernel<<<kNME / 256, 256, 0, stream>>>(W_x, scale, acc);

    producer_kernel<<<(int)(kNNZ / kEnt), kPTh, 0, stream>>>(
        K_sep, rows, cols, u, scale, pairs, counters, capSub, R);

    consumer_kernel<<<kNB * R, 512, 0, stream>>>(
        pairs, counters, partial, capSub, R);

    norm_kernel<<<kNB * (kBSpan / 1024), 256, 0, stream>>>(
        partial, f, acc, (float*)d_out, R);
}

// Round 14
// 249.104 us; speedup vs baseline: 2.3004x; 1.0269x over previous
//
#include <hip/hip_runtime.h>
#include <math.h>

namespace {

constexpr int       kNME    = 262144;
constexpr int       kNDOF   = 524288;
constexpr long long kNNZ    = 16777216;   // kNME * 64
constexpr int       kNB     = 64;         // buckets
constexpr int       kBShift = 13;         // 8192 dofs / bucket
constexpr int       kBSpan  = 8192;
constexpr int       kEnt    = 8192;       // entries per producer block
constexpr int       kPTh   = 1024;        // producer threads
constexpr int       kPerTh  = 8;          // kEnt / kPTh
constexpr int       kCtrStride = 16;      // counters padded to 64 B

constexpr float kEmin    = 1e-9f;
constexpr float kEmax    = 1.0f;
constexpr float kVolfrac = 0.4f;

using u32   = unsigned;
using i32x4 = __attribute__((ext_vector_type(4))) int;
using f32x4 = __attribute__((ext_vector_type(4))) float;
using u32x4 = __attribute__((ext_vector_type(4))) unsigned;

// pair = (localrow:13 bits << 19) | (fp32 bits >> 13)  [sign+exp+10 mantissa]
__device__ __forceinline__ u32 pack32(unsigned localrow, float v) {
    return (localrow << 19) | (__float_as_uint(v) >> 13);
}

// ---------------------------------------------------------------------------
// Kernel 1: per-element SIMP scale + rho partial sum.
// ---------------------------------------------------------------------------
__global__ void scale_kernel(const float* __restrict__ W_x,
                             float* __restrict__ scale,
                             float* __restrict__ rho_sum) {
    int i = blockIdx.x * blockDim.x + threadIdx.x;
    float rho = 0.0f;
    if (i < kNME) {
        float x = W_x[i];
        rho = 1.0f / (1.0f + __expf(-x));
        scale[i] = kEmin + rho * rho * rho * (kEmax - kEmin);
    }
    for (int off = 32; off > 0; off >>= 1) rho += __shfl_down(rho, off, 64);
    __shared__ float partial[4];
    const int lane = threadIdx.x & 63;
    const int wid  = threadIdx.x >> 6;
    if (lane == 0) partial[wid] = rho;
    __syncthreads();
    if (threadIdx.x == 0)
        atomicAdd(rho_sum, partial[0] + partial[1] + partial[2] + partial[3]);
}

// ---------------------------------------------------------------------------
// Producer: 1024 threads x 8 entries = 8192/block.  Round-13 mechanics, but
// NO nontemporal hints: inputs stay L2/L3-resident across graph replays and
// the pairs land in cache for the consumer.
// rv[j]: bits[0:18] = row (19b), bits[19:31] = rank (13b, max 8191).
// ---------------------------------------------------------------------------
__global__ __launch_bounds__(kPTh, 8)
void producer_kernel(const float* __restrict__ K_sep,
                     const int*   __restrict__ rows,
                     const int*   __restrict__ cols,
                     const float* __restrict__ u,
                     const float* __restrict__ scale,
                     u32*         __restrict__ pairs,
                     unsigned*    __restrict__ counters,  // [kNB*R*kCtrStride]
                     unsigned capSub, int R) {
    __shared__ unsigned hist[kNB], ofs[kNB], gbase[kNB];
    __shared__ u32      sorted[kEnt];     // 32 KB

    const int tid = threadIdx.x;
    const int sub = blockIdx.x & (R - 1);
    if (tid < kNB) hist[tid] = 0u;
    __syncthreads();

    const long long i0 =
        (long long)blockIdx.x * kEnt + (long long)tid * kPerTh;
    i32x4 r0 = *((const i32x4*)(rows + i0));
    i32x4 r1 = *((const i32x4*)(rows + i0) + 1);
    i32x4 c0 = *((const i32x4*)(cols + i0));
    i32x4 c1 = *((const i32x4*)(cols + i0) + 1);
    f32x4 k0 = *((const f32x4*)(K_sep + i0));
    f32x4 k1 = *((const f32x4*)(K_sep + i0) + 1);
    const float s = scale[(int)(i0 >> 6)];   // all 8 share one element

    unsigned rv[kPerTh];
    float    vv[kPerTh];
#pragma unroll
    for (int j = 0; j < 4; ++j) {
        rv[j]     = (unsigned)r0[j];  vv[j]     = k0[j] * s * u[c0[j]];
        rv[j + 4] = (unsigned)r1[j];  vv[j + 4] = k1[j] * s * u[c1[j]];
    }
    // Histogram; the returned old value IS this entry's rank in its bucket.
#pragma unroll
    for (int j = 0; j < kPerTh; ++j)
        rv[j] |= atomicAdd(&hist[rv[j] >> kBShift], 1u) << 19;
    __syncthreads();

    // Threads 0..63: exclusive scan over buckets + reserve global sub-ranges.
    if (tid < kNB) {
        unsigned h = hist[tid];
        unsigned x = h;
#pragma unroll
        for (int off = 1; off < kNB; off <<= 1) {
            unsigned y = __shfl_up(x, off, 64);
            if (tid >= off) x += y;
        }
        ofs[tid]   = x - h;
        gbase[tid] = atomicAdd(&counters[(tid * R + sub) * kCtrStride], h);
    }
    __syncthreads();

    // Scatter into sorted LDS order — no atomics (rank precomputed).
#pragma unroll
    for (int j = 0; j < kPerTh; ++j) {
        unsigned row = rv[j] & 0x7FFFFu;
        unsigned b   = row >> kBShift;
        unsigned pos = ofs[b] + (rv[j] >> 19);
        sorted[pos]  = pack32(row & (kBSpan - 1), vv[j]);
    }
    __syncthreads();

    // Coalesced copy-out: 16 waves, 4 bucket runs each (~128 entries/run).
    const int wid = tid >> 6, lane = tid & 63;
    for (int b = wid; b < kNB; b += 16) {
        const unsigned s0 = ofs[b];
        const unsigned n  = hist[b];
        const unsigned g  = gbase[b];
        u32* dst = pairs + (size_t)(b * R + sub) * capSub + g;
        for (unsigned i = lane; i < n; i += 64) {
            if (g + i < capSub) dst[i] = sorted[s0 + i];
        }
    }
}

// ---------------------------------------------------------------------------
// Consumer: block (b, sub) owns one sub-region. 512 threads, u32x4 loads
// (cached — pairs are L2/L3-hot), LDS atomics, private plane store.
// ---------------------------------------------------------------------------
__global__ __launch_bounds__(512, 8)
void consumer_kernel(const u32*      __restrict__ pairs,
                     const unsigned* __restrict__ counters,
                     float*          __restrict__ partial,
                     unsigned capSub, int R) {
    const int b   = blockIdx.x / R;
    const int sub = blockIdx.x - b * R;
    unsigned cnt = counters[(b * R + sub) * kCtrStride];
    if (cnt > capSub) cnt = capSub;

    __shared__ float acc[kBSpan];
    for (int i = threadIdx.x; i < kBSpan; i += 512) acc[i] = 0.0f;
    __syncthreads();

    const u32* p = pairs + (size_t)(b * R + sub) * capSub;
    const unsigned aligned = cnt & ~3u;
    for (unsigned i = 4 * threadIdx.x; i < aligned; i += 2048) {
        u32x4 e = *((const u32x4*)(p + i));
#pragma unroll
        for (int j = 0; j < 4; ++j)
            atomicAdd(&acc[e[j] >> 19], __uint_as_float(e[j] << 13));
    }
    if (threadIdx.x < (cnt - aligned)) {
        u32 e = p[aligned + threadIdx.x];
        atomicAdd(&acc[e >> 19], __uint_as_float(e << 13));
    }
    __syncthreads();

    float* dst = partial + (size_t)(b * R + sub) * kBSpan;
    for (int k = threadIdx.x; k < kBSpan; k += 512) dst[k] = acc[k];
}

// ---------------------------------------------------------------------------
// Norm + finalize: block (b, chunk of 1024 dofs); vectorized sum over R
// planes; done-counter finalize (thread 0 only).
// acc layout: acc[0]=rho_sum, acc[1]=norm_sum, acc[2]=done counter (uint).
// ---------------------------------------------------------------------------
__global__ void norm_kernel(const float* __restrict__ partial,
                            const float* __restrict__ f,
                            float* __restrict__ acc,
                            float* __restrict__ out, int R) {
    const int b  = blockIdx.x >> 3;
    const int i0 = (blockIdx.x & 7) * 1024 + threadIdx.x * 4;
    f32x4 s = {0.0f, 0.0f, 0.0f, 0.0f};
    for (int r = 0; r < R; ++r)
        s += *(const f32x4*)(partial + (size_t)(b * R + r) * kBSpan + i0);
    f32x4 fv = *(const f32x4*)(f + (size_t)b * kBSpan + i0);
    f32x4 d  = s - fv;
    float a = d[0] * d[0] + d[1] * d[1] + d[2] * d[2] + d[3] * d[3];
    for (int off = 32; off > 0; off >>= 1) a += __shfl_down(a, off, 64);
    __shared__ float partial_s[4];
    const int lane = threadIdx.x & 63;
    const int wid  = threadIdx.x >> 6;
    if (lane == 0) partial_s[wid] = a;
    __syncthreads();
    if (threadIdx.x == 0) {
        atomicAdd(&acc[1],
                  partial_s[0] + partial_s[1] + partial_s[2] + partial_s[3]);
        __threadfence();
        unsigned done = atomicAdd((unsigned*)&acc[2], 1u);
        if (done == gridDim.x - 1) {
            float rs = __hip_atomic_load(&acc[0], __ATOMIC_RELAXED,
                                         __HIP_MEMORY_SCOPE_AGENT);
            float ns = __hip_atomic_load(&acc[1], __ATOMIC_RELAXED,
                                         __HIP_MEMORY_SCOPE_AGENT);
            float rho_mean = rs * (1.0f / (float)kNME);
            out[0] = fmaxf(rho_mean - kVolfrac, 0.0f) + sqrtf(ns);
        }
    }
}

// ---------------------------------------------------------------------------
// Fallback path (device atomics) if workspace is too small.
// ---------------------------------------------------------------------------
__global__ void scatter_dev_kernel(const float* __restrict__ K_sep,
                                   const int*   __restrict__ rows,
                                   const int*   __restrict__ cols,
                                   const float* __restrict__ u,
                                   const float* __restrict__ scale,
                                   float* __restrict__ Ku) {
    long long i = (long long)blockIdx.x * blockDim.x + threadIdx.x;
    if (i >= kNNZ) return;
    float s = scale[(int)(i >> 6)];
    atomicAdd(&Ku[rows[i]], K_sep[i] * s * u[cols[i]]);
}

__global__ void norm1_kernel(const float* __restrict__ Ku,
                             const float* __restrict__ f,
                             float* __restrict__ norm_sum) {
    float a = 0.0f;
    for (int i = blockIdx.x * blockDim.x + threadIdx.x; i < kNDOF;
         i += gridDim.x * blockDim.x) {
        float d = Ku[i] - f[i];
        a += d * d;
    }
    for (int off = 32; off > 0; off >>= 1) a += __shfl_down(a, off, 64);
    __shared__ float partial_s[4];
    const int lane = threadIdx.x & 63;
    const int wid  = threadIdx.x >> 6;
    if (lane == 0) partial_s[wid] = a;
    __syncthreads();
    if (threadIdx.x == 0)
        atomicAdd(norm_sum,
                  partial_s[0] + partial_s[1] + partial_s[2] + partial_s[3]);
}

__global__ void finalize_kernel(const float* __restrict__ acc,
                                float* __restrict__ out) {
    if (threadIdx.x == 0 && blockIdx.x == 0) {
        float rho_mean = acc[0] * (1.0f / (float)kNME);
        float vol = fmaxf(rho_mean - kVolfrac, 0.0f);
        out[0] = vol + sqrtf(acc[1]);
    }
}

}  // namespace

extern "C" void kernel_launch(void* const* d_in, const int* in_sizes, int n_in,
                              void* d_out, int out_size, void* d_ws, size_t ws_size,
                              hipStream_t stream) {
    const float* W_x   = (const float*)d_in[0];
    const float* K_sep = (const float*)d_in[1];
    const int*   idx   = (const int*)d_in[2];
    const float* u     = (const float*)d_in[3];
    const float* f     = (const float*)d_in[4];
    const int* rows = idx;
    const int* cols = idx + kNNZ;

    float* ws = (float*)d_ws;
    const size_t avail = ws_size / sizeof(float);

    // Single-chunk config: R=16 subs, margin 2048.
    const int      R      = 16;
    const unsigned capSub = (unsigned)(kNNZ / (kNB * R)) + 2048;
    const size_t   ctrF   = (size_t)kNB * R * kCtrStride;          // 16384
    const size_t   headF  = 16;                                    // acc
    const size_t   partF  = (size_t)kNB * R * kBSpan;              // 8.4M
    const size_t   need   = headF + ctrF + partF + kNME +
                            (size_t)kNB * R * capSub;

    if (need > avail) {
        // Fallback: device-atomic scatter (fits in ~3.2 MB).
        float* Ku    = ws;
        float* scale = ws + kNDOF;
        float* acc   = ws + kNDOF + kNME;
        hipMemsetAsync(ws, 0, (size_t)(kNDOF + kNME + 16) * sizeof(float), stream);
        scale_kernel<<<kNME / 256, 256, 0, stream>>>(W_x, scale, acc);
        scatter_dev_kernel<<<(int)(kNNZ / 256), 256, 0, stream>>>(
            K_sep, rows, cols, u, scale, Ku);
        norm1_kernel<<<2048, 256, 0, stream>>>(Ku, f, acc + 1);
        finalize_kernel<<<1, 64, 0, stream>>>(acc, (float*)d_out);
        return;
    }

    float*    acc      = ws;                          // [16] rho,norm,done
    unsigned* counters = (unsigned*)(ws + headF);     // [kNB*R*kCtrStride]
    float*    partial  = ws + headF + ctrF;           // [kNB*R*kBSpan]
    float*    scale    = partial + partF;             // [kNME]
    u32*      pairs    = (u32*)(scale + kNME);        // [kNB*R*capSub]

    // Zero acc + counters (replay-safe).
    hipMemsetAsync(ws, 0, (headF + ctrF) * sizeof(float), stream);

    scale_kernel<<<kNME / 256, 256, 0, stream>>>(W_x, scale, acc);

    producer_kernel<<<(int)(kNNZ / kEnt), kPTh, 0, stream>>>(
        K_sep, rows, cols, u, scale, pairs, counters, capSub, R);

    consumer_kernel<<<kNB * R, 512, 0, stream>>>(
        pairs, counters, partial, capSub, R);

    norm_kernel<<<kNB * (kBSpan / 1024), 256, 0, stream>>>(
        partial, f, acc, (float*)d_out, R);
}